// Round 2
// baseline (363.143 us; speedup 1.0000x reference)
//
#include <hip/hip_runtime.h>
#include <stdint.h>

typedef unsigned int uint;
typedef unsigned short ushort;

#define NB_FEATURES 512
#define MB_DIM      10240
#define NB_CLASSES  100
#define BATCH       8192
#define KSEL        32
#define NTHR        512
#define VPT         20    // MB_DIM / NTHR

static __device__ __forceinline__ uint f2key(float f) {
    uint u = __float_as_uint(f);
    return u ^ (0x80000000u | (uint)((int)u >> 31));  // monotonic: larger float -> larger uint
}
static __device__ __forceinline__ float key2f(uint k) {
    uint u = k ^ (0x80000000u | (uint)(((int)~k) >> 31));
    return __uint_as_float(u);
}

// ---------------------------------------------------------------------------
// Kernel A: extract per-row nonzero columns of w1, pack 6x10-bit into uint2.
// Rows always have >=6 ones (r >= 6th-largest); >6 only on exact f32 ties ->
// flag bit 31 of .y, extra cols (7th/8th) in ovf[row] (10+10 bits, pad=512).
// Column 512 indexes the zero slot of the replicated LDS x.
// ---------------------------------------------------------------------------
__global__ __launch_bounds__(256) void k_extract(const float* __restrict__ w1,
                                                 uint2* __restrict__ idx2,
                                                 uint* __restrict__ ovf) {
    __shared__ ushort scr[4][8];
    const int gw   = (blockIdx.x * 256 + threadIdx.x) >> 6;  // wave id = row
    const int lane = threadIdx.x & 63;
    const int wid  = (threadIdx.x >> 6) & 3;

    const float* row = w1 + (size_t)gw * NB_FEATURES;
    const float4 a = *(const float4*)(row + lane * 8);
    const float4 b = *(const float4*)(row + lane * 8 + 4);
    const float v[8] = {a.x, a.y, a.z, a.w, b.x, b.y, b.z, b.w};
    int cnt = 0;
#pragma unroll
    for (int j = 0; j < 8; ++j) cnt += (v[j] > 0.5f);
    int p = cnt;
#pragma unroll
    for (int off = 1; off < 64; off <<= 1) {
        int n = __shfl_up(p, off, 64);
        if (lane >= off) p += n;
    }
    const int total = __shfl(p, 63, 64);
    int slot = p - cnt;  // exclusive prefix

    if (lane < 8) scr[wid][lane] = (ushort)NB_FEATURES;  // pad = 512
    __syncthreads();
#pragma unroll
    for (int j = 0; j < 8; ++j) {
        if (v[j] > 0.5f) {
            if (slot < 8) scr[wid][slot] = (ushort)(lane * 8 + j);
            slot++;
        }
    }
    __syncthreads();
    if (lane == 0) {
        const uint c0 = scr[wid][0], c1 = scr[wid][1], c2 = scr[wid][2];
        const uint c3 = scr[wid][3], c4 = scr[wid][4], c5 = scr[wid][5];
        const uint c6 = scr[wid][6], c7 = scr[wid][7];
        uint2 q;
        q.x = c0 | (c1 << 10) | (c2 << 20);
        q.y = c3 | (c4 << 10) | (c5 << 20) | (total > 6 ? 0x80000000u : 0u);
        idx2[gw] = q;
        ovf[gw]  = c6 | (c7 << 10);
    }
}

// ---------------------------------------------------------------------------
// Kernel B: w2t[m][c] = max(w2[c][m], 0)
// ---------------------------------------------------------------------------
__global__ __launch_bounds__(256) void k_w2t(const float* __restrict__ w2,
                                             float* __restrict__ w2t) {
    const int i = blockIdx.x * 256 + threadIdx.x;
    if (i >= NB_CLASSES * MB_DIM) return;
    const int c = i / MB_DIM;
    const int m = i - c * MB_DIM;
    w2t[(size_t)m * NB_CLASSES + c] = fmaxf(w2[i], 0.0f);
}

// ---------------------------------------------------------------------------
// Kernel C: one block (512 threads) per batch row.
// x row staged 32x bank-replicated: xrep[col*32 + bank], lane reads bank=tid&31
// -> lanes l and l+32 share a bank (2-way = free), all gathers conflict-free.
// ---------------------------------------------------------------------------
template <bool USE_W2T>
__global__ __launch_bounds__(NTHR) void k_main(
    const float* __restrict__ x, const uint2* __restrict__ idx2,
    const uint* __restrict__ ovf, const float* __restrict__ w2t,
    const float* __restrict__ w2, const float* __restrict__ b2,
    float* __restrict__ out)
{
    __shared__ float xrep[513 * 32];   // 65664 B, col 512 = zero slot
    __shared__ uint  cand[512];
    __shared__ uint  s_wsum[8];
    __shared__ uint  s_piv[8];
    __shared__ uint  s_thkey;
    __shared__ uint  s_cnt1;
    __shared__ uint  s_pref;
    __shared__ int   s_k;
    __shared__ uint  list_m[64];
    __shared__ float list_v[64];

    const int tid  = threadIdx.x;
    const int lane = tid & 63;
    const int wid  = tid >> 6;           // 0..7
    const int brow = blockIdx.x;

    // 1. stage x row, 32x replicated, rotated bank order (2-way max per write)
    {
        const float xv = x[(size_t)brow * NB_FEATURES + tid];
        const int base = tid << 5;
#pragma unroll
        for (int c = 0; c < 32; ++c) {
            xrep[base + ((c + tid) & 31)] = xv;
        }
        if (tid < 32) xrep[(NB_FEATURES << 5) + tid] = 0.0f;
    }
    __syncthreads();

    const uint bb = (uint)(tid & 31);

    // 2. compute h -> monotonic uint keys in regs (conflict-free gathers)
    uint key[VPT];
#pragma unroll
    for (int i = 0; i < VPT; ++i) {
        const int m = tid + (i << 9);
        const uint2 q = idx2[m];
        float s = xrep[((q.x & 1023u) << 5) | bb]
                + xrep[(((q.x >> 10) & 1023u) << 5) | bb]
                + xrep[(((q.x >> 20) & 1023u) << 5) | bb]
                + xrep[((q.y & 1023u) << 5) | bb]
                + xrep[(((q.y >> 10) & 1023u) << 5) | bb]
                + xrep[(((q.y >> 20) & 1023u) << 5) | bb];
        if (q.y & 0x80000000u) {   // rare tie-overflow row (usually никогда)
            const uint o = ovf[m];
            s += xrep[((o & 1023u) << 5) | bb]
               + xrep[(((o >> 10) & 1023u) << 5) | bb];
        }
        key[i] = f2key(s);
    }

    // 3. pivot: per-thread max -> per-wave bitonic sort(64) -> wave rank-31 ->
    //    pivot = max over 8 waves (provably <= true 32nd-largest)
    {
        uint v = key[0];
#pragma unroll
        for (int i = 1; i < VPT; ++i) v = max(v, key[i]);
#pragma unroll
        for (int k = 2; k <= 64; k <<= 1) {
#pragma unroll
            for (int j = k >> 1; j > 0; j >>= 1) {
                const uint pr = __shfl_xor(v, j, 64);
                const bool lower = (lane & j) == 0;
                const bool asc   = (lane & k) == 0;
                const uint mn = min(v, pr), mx = max(v, pr);
                v = (lower == asc) ? mx : mn;  // descending sort
            }
        }
        if (lane == 31) s_piv[wid] = v;
    }
    __syncthreads();
    uint pivot = s_piv[0];
#pragma unroll
    for (int w = 1; w < 8; ++w) pivot = max(pivot, s_piv[w]);

    // 4. compact candidate keys (>= pivot) into LDS
    int myc = 0;
#pragma unroll
    for (int i = 0; i < VPT; ++i) myc += (key[i] >= pivot) ? 1 : 0;
    int p = myc;
#pragma unroll
    for (int off = 1; off < 64; off <<= 1) {
        int n = __shfl_up(p, off, 64);
        if (lane >= off) p += n;
    }
    if (lane == 63) s_wsum[wid] = (uint)p;
    __syncthreads();
    int base = p - myc;
    for (int w = 0; w < wid; ++w) base += (int)s_wsum[w];
    int ctot = 0;
#pragma unroll
    for (int w = 0; w < 8; ++w) ctot += (int)s_wsum[w];
    {
        int slot = base;
#pragma unroll
        for (int i = 0; i < VPT; ++i) {
            if (key[i] >= pivot) {
                if (slot < 512) cand[slot] = key[i];
                slot++;
            }
        }
    }
    __syncthreads();

    // 5. exact 32nd-largest key; radix fallback for pathological tie floods
    if (ctot <= 512) {
        if (tid < ctot) {
            const uint u = cand[tid];
            int rank = 0;
            for (int j = 0; j < ctot; ++j) {
                const uint vv = cand[j];
                rank += ((vv > u) || (vv == u && j < tid)) ? 1 : 0;
            }
            if (rank == KSEL - 1) s_thkey = u;
        }
    } else {
        if (tid == 0) { s_pref = 0u; s_k = KSEL; }
        __syncthreads();
        for (int bit = 31; bit >= 0; --bit) {
            const uint bmask = 1u << bit;
            const uint dmask = (bit == 31) ? 0u : (0xFFFFFFFFu << (bit + 1));
            const uint pref = s_pref;
            int mc = 0;
#pragma unroll
            for (int i = 0; i < VPT; ++i)
                mc += (((key[i] & dmask) == pref) && (key[i] & bmask)) ? 1 : 0;
            if (tid == 0) s_cnt1 = 0;
            __syncthreads();
            if (mc) atomicAdd(&s_cnt1, (uint)mc);
            __syncthreads();
            if (tid == 0) {
                if ((int)s_cnt1 >= s_k) s_pref = pref | bmask;
                else s_k -= (int)s_cnt1;
            }
            __syncthreads();
        }
        if (tid == 0) s_thkey = s_pref;
    }
    __syncthreads();
    const uint thkey = s_thkey;

    // 6. final compaction of kept entries (key >= thkey) with (m, value)
    int kc = 0;
#pragma unroll
    for (int i = 0; i < VPT; ++i) kc += (key[i] >= thkey) ? 1 : 0;
    int p2 = kc;
#pragma unroll
    for (int off = 1; off < 64; off <<= 1) {
        int n = __shfl_up(p2, off, 64);
        if (lane >= off) p2 += n;
    }
    if (lane == 63) s_wsum[wid] = (uint)p2;
    __syncthreads();
    int kbase = p2 - kc;
    for (int w = 0; w < wid; ++w) kbase += (int)s_wsum[w];
    int ktot = 0;
#pragma unroll
    for (int w = 0; w < 8; ++w) ktot += (int)s_wsum[w];
    {
        int slot = kbase;
#pragma unroll
        for (int i = 0; i < VPT; ++i) {
            if (key[i] >= thkey) {
                if (slot < 64) {
                    list_m[slot] = (uint)(tid + (i << 9));
                    list_v[slot] = key2f(key[i]);
                }
                slot++;
            }
        }
    }
    __syncthreads();

    // 7. out[b][c] = b2[c] + sum_j v_j * max(w2[c][m_j],0)
    const int cnt = ktot < 64 ? ktot : 64;
    if (tid < NB_CLASSES) {
        float acc = b2[tid];
        for (int j = 0; j < cnt; ++j) {
            const uint m = list_m[j];
            const float w = USE_W2T ? w2t[(size_t)m * NB_CLASSES + tid]
                                    : fmaxf(w2[(size_t)tid * MB_DIM + m], 0.0f);
            acc = fmaf(list_v[j], w, acc);
        }
        out[(size_t)brow * NB_CLASSES + tid] = acc;
    }
}

// ---------------------------------------------------------------------------
extern "C" void kernel_launch(void* const* d_in, const int* in_sizes, int n_in,
                              void* d_out, int out_size, void* d_ws, size_t ws_size,
                              hipStream_t stream) {
    const float* x  = (const float*)d_in[0];
    const float* w1 = (const float*)d_in[1];
    const float* w2 = (const float*)d_in[2];
    const float* b2 = (const float*)d_in[3];
    float* out = (float*)d_out;

    uint2* idx2 = (uint2*)d_ws;                          // 10240*8  = 80 KB
    uint*  ovf  = (uint*)((char*)d_ws + 81920);          // 10240*4  = 40 KB
    const size_t W2T_OFF = 131072;                       // 128 KB aligned
    float* w2t = (float*)((char*)d_ws + W2T_OFF);
    const bool use_w2t =
        ws_size >= W2T_OFF + (size_t)MB_DIM * NB_CLASSES * sizeof(float);

    k_extract<<<(MB_DIM * 64) / 256, 256, 0, stream>>>(w1, idx2, ovf);
    if (use_w2t) {
        k_w2t<<<(MB_DIM * NB_CLASSES + 255) / 256, 256, 0, stream>>>(w2, w2t);
        k_main<true><<<BATCH, NTHR, 0, stream>>>(x, idx2, ovf, w2t, w2, b2, out);
    } else {
        k_main<false><<<BATCH, NTHR, 0, stream>>>(x, idx2, ovf, nullptr, w2, b2, out);
    }
}

// Round 3
// 310.326 us; speedup vs baseline: 1.1702x; 1.1702x over previous
//
#include <hip/hip_runtime.h>
#include <stdint.h>

typedef unsigned int uint;
typedef unsigned short ushort;

#define NB_FEATURES 512
#define MB_DIM      10240
#define NB_CLASSES  100
#define BATCH       8192
#define KSEL        32
#define NTHR        512
#define VPT         20    // MB_DIM / NTHR
#define MAXOVF      512

static __device__ __forceinline__ uint f2key(float f) {
    uint u = __float_as_uint(f);
    return u ^ (0x80000000u | (uint)((int)u >> 31));  // monotonic
}
static __device__ __forceinline__ float key2f(uint k) {
    uint u = k ^ (0x80000000u | (uint)(((int)~k) >> 31));
    return __uint_as_float(u);
}

// ---------------------------------------------------------------------------
// Kernel A: extract per-row nonzero columns of w1 (ascending), pack 6x10-bit
// into uint2. Rows with >6 ones (exact-tie rows, ~4 expected) append
// (row, c7|c8<<10) to a global overflow list; pad col = 512 (zero slot).
// ---------------------------------------------------------------------------
__global__ __launch_bounds__(256) void k_extract(const float* __restrict__ w1,
                                                 uint2* __restrict__ idx2,
                                                 uint* __restrict__ ovfc,
                                                 uint2* __restrict__ ovfe) {
    __shared__ ushort scr[4][8];
    const int gw   = (blockIdx.x * 256 + threadIdx.x) >> 6;  // wave id = row
    const int lane = threadIdx.x & 63;
    const int wid  = (threadIdx.x >> 6) & 3;

    const float* row = w1 + (size_t)gw * NB_FEATURES;
    const float4 a = *(const float4*)(row + lane * 8);
    const float4 b = *(const float4*)(row + lane * 8 + 4);
    const float v[8] = {a.x, a.y, a.z, a.w, b.x, b.y, b.z, b.w};
    int cnt = 0;
#pragma unroll
    for (int j = 0; j < 8; ++j) cnt += (v[j] > 0.5f);
    int p = cnt;
#pragma unroll
    for (int off = 1; off < 64; off <<= 1) {
        int n = __shfl_up(p, off, 64);
        if (lane >= off) p += n;
    }
    const int total = __shfl(p, 63, 64);
    int slot = p - cnt;  // exclusive prefix (ascending col order)

    if (lane < 8) scr[wid][lane] = (ushort)NB_FEATURES;  // pad = 512
    __syncthreads();
#pragma unroll
    for (int j = 0; j < 8; ++j) {
        if (v[j] > 0.5f) {
            if (slot < 8) scr[wid][slot] = (ushort)(lane * 8 + j);
            slot++;
        }
    }
    __syncthreads();
    if (lane == 0) {
        const uint c0 = scr[wid][0], c1 = scr[wid][1], c2 = scr[wid][2];
        const uint c3 = scr[wid][3], c4 = scr[wid][4], c5 = scr[wid][5];
        const uint c6 = scr[wid][6], c7 = scr[wid][7];
        uint2 q;
        q.x = c0 | (c1 << 10) | (c2 << 20);
        q.y = c3 | (c4 << 10) | (c5 << 20);
        idx2[gw] = q;
        if (total > 6) {
            const uint s = atomicAdd(ovfc, 1u);
            if (s < MAXOVF) {
                uint2 e; e.x = (uint)gw; e.y = c6 | (c7 << 10);
                ovfe[s] = e;
            }
        }
    }
}

// ---------------------------------------------------------------------------
// Kernel B: w2t[m][c] = max(w2[c][m], 0)
// ---------------------------------------------------------------------------
__global__ __launch_bounds__(256) void k_w2t(const float* __restrict__ w2,
                                             float* __restrict__ w2t) {
    const int i = blockIdx.x * 256 + threadIdx.x;
    if (i >= NB_CLASSES * MB_DIM) return;
    const int c = i / MB_DIM;
    const int m = i - c * MB_DIM;
    w2t[(size_t)m * NB_CLASSES + c] = fmaxf(w2[i], 0.0f);
}

// ---------------------------------------------------------------------------
// Kernel C: one block (512 threads) per batch row. 32x bank-replicated x,
// branchless 6-gather main loop, float-domain top-32 selection.
// ---------------------------------------------------------------------------
template <bool USE_W2T>
__global__ __launch_bounds__(NTHR, 4) void k_main(
    const float* __restrict__ x, const uint2* __restrict__ idx2,
    const uint* __restrict__ ovfc, const uint2* __restrict__ ovfe,
    const float* __restrict__ w2t, const float* __restrict__ w2,
    const float* __restrict__ b2, float* __restrict__ out)
{
    __shared__ float xrep[513 * 32];   // 65664 B; col 512 = zero slot
    __shared__ float cand[512];
    __shared__ uint  s_wsum[8];
    __shared__ float s_piv[8];
    __shared__ float s_thf;
    __shared__ uint  s_cnt1;
    __shared__ uint  s_pref;
    __shared__ int   s_k;
    __shared__ uint  list_m[64];
    __shared__ float list_v[64];

    const int tid  = threadIdx.x;
    const int lane = tid & 63;
    const int wid  = tid >> 6;           // 0..7
    const int brow = blockIdx.x;

    // 1. stage x row, 32x replicated via conflict-free ds_write_b64
    {
        const float xv = x[(size_t)brow * NB_FEATURES + tid];
        float2 xx; xx.x = xv; xx.y = xv;
        const int base = tid << 5;
        const int rot  = (tid << 1) & 31;
#pragma unroll
        for (int j = 0; j < 16; ++j) {
            *(float2*)&xrep[base + ((rot + 2 * j) & 31)] = xx;
        }
        if (tid < 32) xrep[(NB_FEATURES << 5) + tid] = 0.0f;
    }
    __syncthreads();

    const uint bb = (uint)(tid & 31);

    // 2. branchless 6-gather per h value (conflict-free: bank = tid&31)
    float vals[VPT];
#pragma unroll
    for (int i = 0; i < VPT; ++i) {
        const int m = tid + (i << 9);
        const uint2 q = idx2[m];
        float s = xrep[((q.x & 1023u) << 5) | bb];
        s += xrep[(((q.x >> 10) & 1023u) << 5) | bb];
        s += xrep[(((q.x >> 20) & 1023u) << 5) | bb];
        s += xrep[((q.y & 1023u) << 5) | bb];
        s += xrep[(((q.y >> 10) & 1023u) << 5) | bb];
        s += xrep[(((q.y >> 20) & 1023u) << 5) | bb];
        vals[i] = s;
    }

    // 2b. rare tie-overflow fixup (usually novf == 0; compile-time indexing)
    {
        uint novf = *ovfc;
        if (novf > MAXOVF) novf = MAXOVF;
        for (uint e = 0; e < novf; ++e) {
            const uint2 ent = ovfe[e];
            const float add = xrep[((ent.y & 1023u) << 5) | bb]
                            + xrep[(((ent.y >> 10) & 1023u) << 5) | bb];
            const int em = (int)ent.x;
#pragma unroll
            for (int i = 0; i < VPT; ++i) {
                if (em == tid + (i << 9)) vals[i] += add;
            }
        }
    }

    // 3. pivot: per-thread max -> per-wave bitonic sort(64) -> wave rank-31 ->
    //    pivot = max over 8 waves (provably <= true 32nd-largest)
    {
        float v = vals[0];
#pragma unroll
        for (int i = 1; i < VPT; ++i) v = fmaxf(v, vals[i]);
#pragma unroll
        for (int k = 2; k <= 64; k <<= 1) {
#pragma unroll
            for (int j = k >> 1; j > 0; j >>= 1) {
                const float pr = __shfl_xor(v, j, 64);
                const bool lower = (lane & j) == 0;
                const bool asc   = (lane & k) == 0;
                const float mn = fminf(v, pr), mx = fmaxf(v, pr);
                v = (lower == asc) ? mx : mn;  // descending
            }
        }
        if (lane == 31) s_piv[wid] = v;
    }
    __syncthreads();
    float pivot = s_piv[0];
#pragma unroll
    for (int w = 1; w < 8; ++w) pivot = fmaxf(pivot, s_piv[w]);

    // 4. compact candidates (>= pivot) into LDS
    int myc = 0;
#pragma unroll
    for (int i = 0; i < VPT; ++i) myc += (vals[i] >= pivot) ? 1 : 0;
    int p = myc;
#pragma unroll
    for (int off = 1; off < 64; off <<= 1) {
        int n = __shfl_up(p, off, 64);
        if (lane >= off) p += n;
    }
    if (lane == 63) s_wsum[wid] = (uint)p;
    __syncthreads();
    int base = p - myc;
    for (int w = 0; w < wid; ++w) base += (int)s_wsum[w];
    int ctot = 0;
#pragma unroll
    for (int w = 0; w < 8; ++w) ctot += (int)s_wsum[w];
    {
        int slot = base;
#pragma unroll
        for (int i = 0; i < VPT; ++i) {
            if (vals[i] >= pivot) {
                if (slot < 512) cand[slot] = vals[i];
                slot++;
            }
        }
    }
    __syncthreads();

    // 5. exact 32nd-largest (ties -> same float threshold as reference)
    if (ctot <= 512) {
        if (tid < ctot) {
            const float u = cand[tid];
            int rank = 0;
            for (int j = 0; j < ctot; ++j) {
                const float vv = cand[j];
                rank += ((vv > u) || (vv == u && j < tid)) ? 1 : 0;
            }
            if (rank == KSEL - 1) s_thf = u;
        }
    } else {  // pathological tie flood: exact radix on monotonic keys
        if (tid == 0) { s_pref = 0u; s_k = KSEL; }
        __syncthreads();
        for (int bit = 31; bit >= 0; --bit) {
            const uint bmask = 1u << bit;
            const uint dmask = (bit == 31) ? 0u : (0xFFFFFFFFu << (bit + 1));
            const uint pref = s_pref;
            int mc = 0;
#pragma unroll
            for (int i = 0; i < VPT; ++i) {
                const uint k = f2key(vals[i]);
                mc += (((k & dmask) == pref) && (k & bmask)) ? 1 : 0;
            }
            if (tid == 0) s_cnt1 = 0;
            __syncthreads();
            if (mc) atomicAdd(&s_cnt1, (uint)mc);
            __syncthreads();
            if (tid == 0) {
                if ((int)s_cnt1 >= s_k) s_pref = pref | bmask;
                else s_k -= (int)s_cnt1;
            }
            __syncthreads();
        }
        if (tid == 0) s_thf = key2f(s_pref);
    }
    __syncthreads();
    const float thf = s_thf;

    // 6. final compaction of kept entries (vals >= thf), zero-padded to 64
    if (tid < 64) { list_m[tid] = 0u; list_v[tid] = 0.0f; }
    int kc = 0;
#pragma unroll
    for (int i = 0; i < VPT; ++i) kc += (vals[i] >= thf) ? 1 : 0;
    int p2 = kc;
#pragma unroll
    for (int off = 1; off < 64; off <<= 1) {
        int n = __shfl_up(p2, off, 64);
        if (lane >= off) p2 += n;
    }
    if (lane == 63) s_wsum[wid] = (uint)p2;
    __syncthreads();
    int kbase = p2 - kc;
    for (int w = 0; w < wid; ++w) kbase += (int)s_wsum[w];
    {
        int slot = kbase;
#pragma unroll
        for (int i = 0; i < VPT; ++i) {
            if (vals[i] >= thf) {
                if (slot < 64) {
                    list_m[slot] = (uint)(tid + (i << 9));
                    list_v[slot] = vals[i];
                }
                slot++;
            }
        }
    }
    __syncthreads();

    // 7. out[b][c] = b2[c] + sum_j v_j * w2t[m_j][c]  (fully unrolled, padded)
    if (tid < NB_CLASSES) {
        float a0 = b2[tid], a1 = 0.0f;
#pragma unroll
        for (int j = 0; j < 64; j += 2) {
            const uint m0 = list_m[j], m1 = list_m[j + 1];
            float w0, w1;
            if (USE_W2T) {
                w0 = w2t[(size_t)m0 * NB_CLASSES + tid];
                w1 = w2t[(size_t)m1 * NB_CLASSES + tid];
            } else {
                w0 = fmaxf(w2[(size_t)tid * MB_DIM + m0], 0.0f);
                w1 = fmaxf(w2[(size_t)tid * MB_DIM + m1], 0.0f);
            }
            a0 = fmaf(list_v[j],     w0, a0);
            a1 = fmaf(list_v[j + 1], w1, a1);
        }
        out[(size_t)brow * NB_CLASSES + tid] = a0 + a1;
    }
}

// ---------------------------------------------------------------------------
extern "C" void kernel_launch(void* const* d_in, const int* in_sizes, int n_in,
                              void* d_out, int out_size, void* d_ws, size_t ws_size,
                              hipStream_t stream) {
    const float* x  = (const float*)d_in[0];
    const float* w1 = (const float*)d_in[1];
    const float* w2 = (const float*)d_in[2];
    const float* b2 = (const float*)d_in[3];
    float* out = (float*)d_out;

    uint2* idx2 = (uint2*)d_ws;                            // 81920 B
    uint*  ovfc = (uint*)((char*)d_ws + 81920);            // 4 B
    uint2* ovfe = (uint2*)((char*)d_ws + 81928);           // 4096 B
    const size_t W2T_OFF = 131072;
    float* w2t = (float*)((char*)d_ws + W2T_OFF);
    const bool use_w2t =
        ws_size >= W2T_OFF + (size_t)MB_DIM * NB_CLASSES * sizeof(float);

    hipMemsetAsync(ovfc, 0, sizeof(uint), stream);
    k_extract<<<(MB_DIM * 64) / 256, 256, 0, stream>>>(w1, idx2, ovfc, ovfe);
    if (use_w2t) {
        k_w2t<<<(MB_DIM * NB_CLASSES + 255) / 256, 256, 0, stream>>>(w2, w2t);
        k_main<true><<<BATCH, NTHR, 0, stream>>>(x, idx2, ovfc, ovfe, w2t, w2, b2, out);
    } else {
        k_main<false><<<BATCH, NTHR, 0, stream>>>(x, idx2, ovfc, ovfe, nullptr, w2, b2, out);
    }
}

// Round 4
// 293.276 us; speedup vs baseline: 1.2382x; 1.0581x over previous
//
#include <hip/hip_runtime.h>
#include <stdint.h>

typedef unsigned int uint;
typedef unsigned short ushort;

#define NB_FEATURES 512
#define MB_DIM      10240
#define NB_CLASSES  100
#define BATCH       8192
#define KSEL        32
#define NTHR        512
#define VPT         20    // MB_DIM / NTHR (per row)
#define MAXOVF      512

static __device__ __forceinline__ uint f2key(float f) {
    uint u = __float_as_uint(f);
    return u ^ (0x80000000u | (uint)((int)u >> 31));  // monotonic
}
static __device__ __forceinline__ float key2f(uint k) {
    uint u = k ^ (0x80000000u | (uint)(((int)~k) >> 31));
    return __uint_as_float(u);
}

// ---------------------------------------------------------------------------
// Kernel A: extract per-row nonzero columns of w1 (ascending), pack 6x10-bit
// into uint2. Rows with >6 ones (exact-tie rows, ~4 expected) append
// (row, c7|c8<<10) to a global overflow list; pad col = 512 (zero slot).
// ---------------------------------------------------------------------------
__global__ __launch_bounds__(256) void k_extract(const float* __restrict__ w1,
                                                 uint2* __restrict__ idx2,
                                                 uint* __restrict__ ovfc,
                                                 uint2* __restrict__ ovfe) {
    __shared__ ushort scr[4][8];
    const int gw   = (blockIdx.x * 256 + threadIdx.x) >> 6;  // wave id = row
    const int lane = threadIdx.x & 63;
    const int wid  = (threadIdx.x >> 6) & 3;

    const float* row = w1 + (size_t)gw * NB_FEATURES;
    const float4 a = *(const float4*)(row + lane * 8);
    const float4 b = *(const float4*)(row + lane * 8 + 4);
    const float v[8] = {a.x, a.y, a.z, a.w, b.x, b.y, b.z, b.w};
    int cnt = 0;
#pragma unroll
    for (int j = 0; j < 8; ++j) cnt += (v[j] > 0.5f);
    int p = cnt;
#pragma unroll
    for (int off = 1; off < 64; off <<= 1) {
        int n = __shfl_up(p, off, 64);
        if (lane >= off) p += n;
    }
    const int total = __shfl(p, 63, 64);
    int slot = p - cnt;  // exclusive prefix (ascending col order)

    if (lane < 8) scr[wid][lane] = (ushort)NB_FEATURES;  // pad = 512
    __syncthreads();
#pragma unroll
    for (int j = 0; j < 8; ++j) {
        if (v[j] > 0.5f) {
            if (slot < 8) scr[wid][slot] = (ushort)(lane * 8 + j);
            slot++;
        }
    }
    __syncthreads();
    if (lane == 0) {
        const uint c0 = scr[wid][0], c1 = scr[wid][1], c2 = scr[wid][2];
        const uint c3 = scr[wid][3], c4 = scr[wid][4], c5 = scr[wid][5];
        const uint c6 = scr[wid][6], c7 = scr[wid][7];
        uint2 q;
        q.x = c0 | (c1 << 10) | (c2 << 20);
        q.y = c3 | (c4 << 10) | (c5 << 20);
        idx2[gw] = q;
        if (total > 6) {
            const uint s = atomicAdd(ovfc, 1u);
            if (s < MAXOVF) {
                uint2 e; e.x = (uint)gw; e.y = c6 | (c7 << 10);
                ovfe[s] = e;
            }
        }
    }
}

// ---------------------------------------------------------------------------
// Kernel B: w2t[m][c] = max(w2[c][m], 0)
// ---------------------------------------------------------------------------
__global__ __launch_bounds__(256) void k_w2t(const float* __restrict__ w2,
                                             float* __restrict__ w2t) {
    const int i = blockIdx.x * 256 + threadIdx.x;
    if (i >= NB_CLASSES * MB_DIM) return;
    const int c = i / MB_DIM;
    const int m = i - c * MB_DIM;
    w2t[(size_t)m * NB_CLASSES + c] = fmaxf(w2[i], 0.0f);
}

// ---------------------------------------------------------------------------
// Kernel C: one block (512 threads) per TWO batch rows. x of both rows packed
// as float2, 8x bank-replicated (XOR rotation) -> 32.8 KB LDS, 4 blocks/CU,
// 32 waves/CU. One ds_read_b64 feeds both rows.
// ---------------------------------------------------------------------------
template <bool USE_W2T>
__global__ __launch_bounds__(NTHR, 4) void k_main(
    const float* __restrict__ x, const uint2* __restrict__ idx2,
    const uint* __restrict__ ovfc, const uint2* __restrict__ ovfe,
    const float* __restrict__ w2t, const float* __restrict__ w2,
    const float* __restrict__ b2, float* __restrict__ out)
{
    __shared__ float2 xrep[513 * 8];   // 32832 B; col 512 = zero slot
    __shared__ float  cand[512];
    __shared__ uint   s_wsum[8];
    __shared__ float  s_piv[8];
    __shared__ float  s_thf[2];
    __shared__ uint   s_cnt1;
    __shared__ uint   s_pref;
    __shared__ int    s_k;
    __shared__ uint   list_m[2][64];
    __shared__ float  list_v[2][64];

    const int tid  = threadIdx.x;
    const int lane = tid & 63;
    const int wid  = tid >> 6;           // 0..7
    const int brow = blockIdx.x * 2;

    // 1. stage both rows (float2), 8x replicated with rotated replica order
    {
        float2 xv;
        xv.x = x[(size_t)brow * NB_FEATURES + tid];
        xv.y = x[(size_t)(brow + 1) * NB_FEATURES + tid];
        const int r0 = (tid >> 3) & 7;
#pragma unroll
        for (int j = 0; j < 8; ++j) {
            xrep[(tid << 3) + ((r0 + j) & 7)] = xv;
        }
        if (tid < 8) { float2 z; z.x = 0.0f; z.y = 0.0f; xrep[(NB_FEATURES << 3) + tid] = z; }
        if (tid < 64) {
            list_m[0][tid] = 0u; list_v[0][tid] = 0.0f;
            list_m[1][tid] = 0u; list_v[1][tid] = 0.0f;
        }
    }
    __syncthreads();

    // 2. branchless 6-gather per m, one b64 read covers both rows
    float2 va[VPT];
#pragma unroll
    for (int i = 0; i < VPT; ++i) {
        const int m = tid + (i << 9);
        const uint2 q = idx2[m];
        const uint c0 = q.x & 1023u, c1 = (q.x >> 10) & 1023u, c2 = (q.x >> 20) & 1023u;
        const uint c3 = q.y & 1023u, c4 = (q.y >> 10) & 1023u, c5 = (q.y >> 20) & 1023u;
        const uint t = (uint)tid;
        const float2 g0 = xrep[(c0 << 3) | ((t ^ c0) & 7u)];
        const float2 g1 = xrep[(c1 << 3) | ((t ^ c1) & 7u)];
        const float2 g2 = xrep[(c2 << 3) | ((t ^ c2) & 7u)];
        const float2 g3 = xrep[(c3 << 3) | ((t ^ c3) & 7u)];
        const float2 g4 = xrep[(c4 << 3) | ((t ^ c4) & 7u)];
        const float2 g5 = xrep[(c5 << 3) | ((t ^ c5) & 7u)];
        va[i].x = ((g0.x + g1.x) + (g2.x + g3.x)) + (g4.x + g5.x);
        va[i].y = ((g0.y + g1.y) + (g2.y + g3.y)) + (g4.y + g5.y);
    }

    // 2b. rare tie-overflow fixup (usually novf == 0)
    {
        uint novf = *ovfc;
        if (novf > MAXOVF) novf = MAXOVF;
        for (uint e = 0; e < novf; ++e) {
            const uint2 ent = ovfe[e];
            const uint o0 = ent.y & 1023u, o1 = (ent.y >> 10) & 1023u;
            const uint t = (uint)tid;
            const float2 a0 = xrep[(o0 << 3) | ((t ^ o0) & 7u)];
            const float2 a1 = xrep[(o1 << 3) | ((t ^ o1) & 7u)];
            const int em = (int)ent.x;
#pragma unroll
            for (int i = 0; i < VPT; ++i) {
                if (em == tid + (i << 9)) {
                    va[i].x += a0.x + a1.x;
                    va[i].y += a0.y + a1.y;
                }
            }
        }
    }

    // 3-6. per-row top-32 selection (unrolled over the 2 packed rows)
#pragma unroll
    for (int r = 0; r < 2; ++r) {
        // 3. pivot: thread max -> wave bitonic sort(64) -> wave rank-31 ->
        //    pivot = max over 8 waves (provably <= true 32nd-largest)
        {
            float v = (r == 0) ? va[0].x : va[0].y;
#pragma unroll
            for (int i = 1; i < VPT; ++i) v = fmaxf(v, (r == 0) ? va[i].x : va[i].y);
#pragma unroll
            for (int k = 2; k <= 64; k <<= 1) {
#pragma unroll
                for (int j = k >> 1; j > 0; j >>= 1) {
                    const float pr = __shfl_xor(v, j, 64);
                    const bool lower = (lane & j) == 0;
                    const bool asc   = (lane & k) == 0;
                    const float mn = fminf(v, pr), mx = fmaxf(v, pr);
                    v = (lower == asc) ? mx : mn;  // descending
                }
            }
            if (lane == 31) s_piv[wid] = v;
        }
        __syncthreads();
        float pivot = s_piv[0];
#pragma unroll
        for (int w = 1; w < 8; ++w) pivot = fmaxf(pivot, s_piv[w]);

        // 4. compact candidates (>= pivot) into LDS
        int myc = 0;
#pragma unroll
        for (int i = 0; i < VPT; ++i)
            myc += (((r == 0) ? va[i].x : va[i].y) >= pivot) ? 1 : 0;
        int p = myc;
#pragma unroll
        for (int off = 1; off < 64; off <<= 1) {
            int n = __shfl_up(p, off, 64);
            if (lane >= off) p += n;
        }
        if (lane == 63) s_wsum[wid] = (uint)p;
        __syncthreads();
        int base = p - myc;
        for (int w = 0; w < wid; ++w) base += (int)s_wsum[w];
        int ctot = 0;
#pragma unroll
        for (int w = 0; w < 8; ++w) ctot += (int)s_wsum[w];
        {
            int slot = base;
#pragma unroll
            for (int i = 0; i < VPT; ++i) {
                const float v = (r == 0) ? va[i].x : va[i].y;
                if (v >= pivot) {
                    if (slot < 512) cand[slot] = v;
                    slot++;
                }
            }
        }
        __syncthreads();

        // 5. exact 32nd-largest (ties -> same float threshold as reference)
        if (ctot <= 512) {
            if (tid < ctot) {
                const float u = cand[tid];
                int rank = 0;
                for (int j = 0; j < ctot; ++j) {
                    const float vv = cand[j];
                    rank += ((vv > u) || (vv == u && j < tid)) ? 1 : 0;
                }
                if (rank == KSEL - 1) s_thf[r] = u;
            }
        } else {  // pathological tie flood: exact radix on monotonic keys
            if (tid == 0) { s_pref = 0u; s_k = KSEL; }
            __syncthreads();
            for (int bit = 31; bit >= 0; --bit) {
                const uint bmask = 1u << bit;
                const uint dmask = (bit == 31) ? 0u : (0xFFFFFFFFu << (bit + 1));
                const uint pref = s_pref;
                int mc = 0;
#pragma unroll
                for (int i = 0; i < VPT; ++i) {
                    const uint k = f2key((r == 0) ? va[i].x : va[i].y);
                    mc += (((k & dmask) == pref) && (k & bmask)) ? 1 : 0;
                }
                if (tid == 0) s_cnt1 = 0;
                __syncthreads();
                if (mc) atomicAdd(&s_cnt1, (uint)mc);
                __syncthreads();
                if (tid == 0) {
                    if ((int)s_cnt1 >= s_k) s_pref = pref | bmask;
                    else s_k -= (int)s_cnt1;
                }
                __syncthreads();
            }
            if (tid == 0) s_thf[r] = key2f(s_pref);
        }
        __syncthreads();
        const float thf = s_thf[r];

        // 6. final compaction of kept entries (>= thf) into list[r]
        int kc = 0;
#pragma unroll
        for (int i = 0; i < VPT; ++i)
            kc += (((r == 0) ? va[i].x : va[i].y) >= thf) ? 1 : 0;
        int p2 = kc;
#pragma unroll
        for (int off = 1; off < 64; off <<= 1) {
            int n = __shfl_up(p2, off, 64);
            if (lane >= off) p2 += n;
        }
        if (lane == 63) s_wsum[wid] = (uint)p2;
        __syncthreads();
        int kbase = p2 - kc;
        for (int w = 0; w < wid; ++w) kbase += (int)s_wsum[w];
        {
            int slot = kbase;
#pragma unroll
            for (int i = 0; i < VPT; ++i) {
                const float v = (r == 0) ? va[i].x : va[i].y;
                if (v >= thf) {
                    if (slot < 64) {
                        list_m[r][slot] = (uint)(tid + (i << 9));
                        list_v[r][slot] = v;
                    }
                    slot++;
                }
            }
        }
        __syncthreads();
    }

    // 7. output: threads 0..99 -> row A, threads 256..355 -> row B
    const int grp = tid >> 8;        // 0 or 1
    const int c   = tid & 255;
    if (c < NB_CLASSES) {
        float a0 = b2[c], a1 = 0.0f;
#pragma unroll
        for (int j = 0; j < 64; j += 2) {
            const uint m0 = list_m[grp][j], m1 = list_m[grp][j + 1];
            float w0, w1;
            if (USE_W2T) {
                w0 = w2t[(size_t)m0 * NB_CLASSES + c];
                w1 = w2t[(size_t)m1 * NB_CLASSES + c];
            } else {
                w0 = fmaxf(w2[(size_t)c * MB_DIM + m0], 0.0f);
                w1 = fmaxf(w2[(size_t)c * MB_DIM + m1], 0.0f);
            }
            a0 = fmaf(list_v[grp][j],     w0, a0);
            a1 = fmaf(list_v[grp][j + 1], w1, a1);
        }
        out[(size_t)(brow + grp) * NB_CLASSES + c] = a0 + a1;
    }
}

// ---------------------------------------------------------------------------
extern "C" void kernel_launch(void* const* d_in, const int* in_sizes, int n_in,
                              void* d_out, int out_size, void* d_ws, size_t ws_size,
                              hipStream_t stream) {
    const float* x  = (const float*)d_in[0];
    const float* w1 = (const float*)d_in[1];
    const float* w2 = (const float*)d_in[2];
    const float* b2 = (const float*)d_in[3];
    float* out = (float*)d_out;

    uint2* idx2 = (uint2*)d_ws;                            // 81920 B
    uint*  ovfc = (uint*)((char*)d_ws + 81920);            // 4 B
    uint2* ovfe = (uint2*)((char*)d_ws + 81928);           // 4096 B
    const size_t W2T_OFF = 131072;
    float* w2t = (float*)((char*)d_ws + W2T_OFF);
    const bool use_w2t =
        ws_size >= W2T_OFF + (size_t)MB_DIM * NB_CLASSES * sizeof(float);

    hipMemsetAsync(ovfc, 0, sizeof(uint), stream);
    k_extract<<<(MB_DIM * 64) / 256, 256, 0, stream>>>(w1, idx2, ovfc, ovfe);
    if (use_w2t) {
        k_w2t<<<(MB_DIM * NB_CLASSES + 255) / 256, 256, 0, stream>>>(w2, w2t);
        k_main<true><<<BATCH / 2, NTHR, 0, stream>>>(x, idx2, ovfc, ovfe, w2t, w2, b2, out);
    } else {
        k_main<false><<<BATCH / 2, NTHR, 0, stream>>>(x, idx2, ovfc, ovfe, nullptr, w2, b2, out);
    }
}

// Round 5
// 193.669 us; speedup vs baseline: 1.8751x; 1.5143x over previous
//
#include <hip/hip_runtime.h>
#include <stdint.h>

typedef unsigned int uint;
typedef unsigned short ushort;

#define NB_FEATURES 512
#define MB_DIM      10240
#define NB_CLASSES  100
#define BATCH       8192
#define KSEL        32
#define NTHR        256
#define VPT         40    // MB_DIM / NTHR
#define MAXOVF      512

static __device__ __forceinline__ uint f2key(float f) {
    uint u = __float_as_uint(f);
    return u ^ (0x80000000u | (uint)((int)u >> 31));  // monotonic
}
static __device__ __forceinline__ float key2f(uint k) {
    uint u = k ^ (0x80000000u | (uint)(((int)~k) >> 31));
    return __uint_as_float(u);
}

// ---------------------------------------------------------------------------
// Kernel A: extract per-row nonzero columns of w1 (ascending), pack 6x10-bit
// into uint2. Rows with >6 ones (exact-tie rows, rare) append (row, c7|c8<<10)
// to a global overflow list; pad col = 512 (zero slot in xs4).
// ---------------------------------------------------------------------------
__global__ __launch_bounds__(256) void k_extract(const float* __restrict__ w1,
                                                 uint2* __restrict__ idx2,
                                                 uint* __restrict__ ovfc,
                                                 uint2* __restrict__ ovfe) {
    __shared__ ushort scr[4][8];
    const int gw   = (blockIdx.x * 256 + threadIdx.x) >> 6;  // wave id = row
    const int lane = threadIdx.x & 63;
    const int wid  = (threadIdx.x >> 6) & 3;

    const float* row = w1 + (size_t)gw * NB_FEATURES;
    const float4 a = *(const float4*)(row + lane * 8);
    const float4 b = *(const float4*)(row + lane * 8 + 4);
    const float v[8] = {a.x, a.y, a.z, a.w, b.x, b.y, b.z, b.w};
    int cnt = 0;
#pragma unroll
    for (int j = 0; j < 8; ++j) cnt += (v[j] > 0.5f);
    int p = cnt;
#pragma unroll
    for (int off = 1; off < 64; off <<= 1) {
        int n = __shfl_up(p, off, 64);
        if (lane >= off) p += n;
    }
    const int total = __shfl(p, 63, 64);
    int slot = p - cnt;  // exclusive prefix (ascending col order)

    if (lane < 8) scr[wid][lane] = (ushort)NB_FEATURES;  // pad = 512
    __syncthreads();
#pragma unroll
    for (int j = 0; j < 8; ++j) {
        if (v[j] > 0.5f) {
            if (slot < 8) scr[wid][slot] = (ushort)(lane * 8 + j);
            slot++;
        }
    }
    __syncthreads();
    if (lane == 0) {
        const uint c0 = scr[wid][0], c1 = scr[wid][1], c2 = scr[wid][2];
        const uint c3 = scr[wid][3], c4 = scr[wid][4], c5 = scr[wid][5];
        const uint c6 = scr[wid][6], c7 = scr[wid][7];
        uint2 q;
        q.x = c0 | (c1 << 10) | (c2 << 20);
        q.y = c3 | (c4 << 10) | (c5 << 20);
        idx2[gw] = q;
        if (total > 6) {
            const uint s = atomicAdd(ovfc, 1u);
            if (s < MAXOVF) {
                uint2 e; e.x = (uint)gw; e.y = c6 | (c7 << 10);
                ovfe[s] = e;
            }
        }
    }
}

// ---------------------------------------------------------------------------
// Kernel B: w2t[m][c] = max(w2[c][m], 0)
// ---------------------------------------------------------------------------
__global__ __launch_bounds__(256) void k_w2t(const float* __restrict__ w2,
                                             float* __restrict__ w2t) {
    const int i = blockIdx.x * 256 + threadIdx.x;
    if (i >= NB_CLASSES * MB_DIM) return;
    const int c = i / MB_DIM;
    const int m = i - c * MB_DIM;
    w2t[(size_t)m * NB_CLASSES + c] = fmaxf(w2[i], 0.0f);
}

// ---------------------------------------------------------------------------
// Kernel C: one block (256 threads) per batch row. x staged 4x-replicated:
// xs4[col*4 + r], reader uses fixed r = tid&3 (folded into base pointer).
// bank = ((col&7)<<2)|(tid&3): collisions only among 16 same-(tid&3) lanes
// sharing col&7 -> expected 2-way (free). LDS ~11 KB -> 8 blocks/CU.
// ---------------------------------------------------------------------------
template <bool USE_W2T>
__global__ __launch_bounds__(NTHR) void k_main(
    const float* __restrict__ x, const uint2* __restrict__ idx2,
    const uint* __restrict__ ovfc, const uint2* __restrict__ ovfe,
    const float* __restrict__ w2t, const float* __restrict__ w2,
    const float* __restrict__ b2, float* __restrict__ out)
{
    __shared__ float xs4[513 * 4];   // 8208 B; col 512 = zero slot
    __shared__ float cand[512];
    __shared__ uint  s_wsum[4];
    __shared__ float s_piv[4];
    __shared__ float s_thf;
    __shared__ uint  s_cnt1;
    __shared__ uint  s_pref;
    __shared__ int   s_k;
    __shared__ uint  list_m[64];
    __shared__ float list_v[64];

    const int tid  = threadIdx.x;
    const int lane = tid & 63;
    const int wid  = tid >> 6;           // 0..3
    const int brow = blockIdx.x;

    // 1. stage x row, 4x replicated (b128 writes, uniform bank load)
    {
        const float v0 = x[(size_t)brow * NB_FEATURES + tid];
        const float v1 = x[(size_t)brow * NB_FEATURES + tid + 256];
        float4 f0; f0.x = v0; f0.y = v0; f0.z = v0; f0.w = v0;
        float4 f1; f1.x = v1; f1.y = v1; f1.z = v1; f1.w = v1;
        *(float4*)&xs4[tid << 2]         = f0;
        *(float4*)&xs4[(tid + 256) << 2] = f1;
        if (tid == 0) {
            float4 z; z.x = 0.0f; z.y = 0.0f; z.z = 0.0f; z.w = 0.0f;
            *(float4*)&xs4[512 << 2] = z;
        }
        if (tid < 64) { list_m[tid] = 0u; list_v[tid] = 0.0f; }
    }
    __syncthreads();

    const float* xb = xs4 + (tid & 3);   // fixed replica per thread

    // 2. branchless 6-gather per m (bfe + lshl_add addressing)
    float vals[VPT];
#pragma unroll
    for (int i = 0; i < VPT; ++i) {
        const int m = tid + (i << 8);
        const uint2 q = idx2[m];
        float s = xb[(q.x & 1023u) << 2];
        s += xb[((q.x >> 10) & 1023u) << 2];
        s += xb[((q.x >> 20) & 1023u) << 2];
        s += xb[(q.y & 1023u) << 2];
        s += xb[((q.y >> 10) & 1023u) << 2];
        s += xb[((q.y >> 20) & 1023u) << 2];
        vals[i] = s;
    }

    // 2b. rare tie-overflow fixup (usually novf == 0; compile-time indexing)
    {
        uint novf = *ovfc;
        if (novf > MAXOVF) novf = MAXOVF;
        for (uint e = 0; e < novf; ++e) {
            const uint2 ent = ovfe[e];
            const float add = xb[(ent.y & 1023u) << 2]
                            + xb[((ent.y >> 10) & 1023u) << 2];
            const int em = (int)ent.x;
#pragma unroll
            for (int i = 0; i < VPT; ++i) {
                if (em == tid + (i << 8)) vals[i] += add;
            }
        }
    }

    // 3. pivot: thread max -> wave bitonic sort(64) -> wave rank-31 ->
    //    pivot = max over 4 waves (provably <= true 32nd-largest)
    {
        float v = vals[0];
#pragma unroll
        for (int i = 1; i < VPT; ++i) v = fmaxf(v, vals[i]);
#pragma unroll
        for (int k = 2; k <= 64; k <<= 1) {
#pragma unroll
            for (int j = k >> 1; j > 0; j >>= 1) {
                const float pr = __shfl_xor(v, j, 64);
                const bool lower = (lane & j) == 0;
                const bool asc   = (lane & k) == 0;
                const float mn = fminf(v, pr), mx = fmaxf(v, pr);
                v = (lower == asc) ? mx : mn;  // descending
            }
        }
        if (lane == 31) s_piv[wid] = v;
    }
    __syncthreads();
    float pivot = fmaxf(fmaxf(s_piv[0], s_piv[1]), fmaxf(s_piv[2], s_piv[3]));

    // 4. compact candidates (>= pivot) into LDS
    int myc = 0;
#pragma unroll
    for (int i = 0; i < VPT; ++i) myc += (vals[i] >= pivot) ? 1 : 0;
    int p = myc;
#pragma unroll
    for (int off = 1; off < 64; off <<= 1) {
        int n = __shfl_up(p, off, 64);
        if (lane >= off) p += n;
    }
    if (lane == 63) s_wsum[wid] = (uint)p;
    __syncthreads();
    int base = p - myc;
    for (int w = 0; w < wid; ++w) base += (int)s_wsum[w];
    const int ctot = (int)(s_wsum[0] + s_wsum[1] + s_wsum[2] + s_wsum[3]);
    {
        int slot = base;
#pragma unroll
        for (int i = 0; i < VPT; ++i) {
            if (vals[i] >= pivot) {
                if (slot < 512) cand[slot] = vals[i];
                slot++;
            }
        }
    }
    __syncthreads();

    // 5. exact 32nd-largest (ties -> same float threshold as reference);
    //    strided so 256 threads cover up to 512 candidates.
    if (ctot <= 512) {
        for (int pos = tid; pos < ctot; pos += NTHR) {
            const float u = cand[pos];
            int rank = 0;
            for (int j = 0; j < ctot; ++j) {
                const float vv = cand[j];
                rank += ((vv > u) || (vv == u && j < pos)) ? 1 : 0;
            }
            if (rank == KSEL - 1) s_thf = u;
        }
    } else {  // pathological tie flood: exact radix on monotonic keys
        if (tid == 0) { s_pref = 0u; s_k = KSEL; }
        __syncthreads();
        for (int bit = 31; bit >= 0; --bit) {
            const uint bmask = 1u << bit;
            const uint dmask = (bit == 31) ? 0u : (0xFFFFFFFFu << (bit + 1));
            const uint pref = s_pref;
            int mc = 0;
#pragma unroll
            for (int i = 0; i < VPT; ++i) {
                const uint k = f2key(vals[i]);
                mc += (((k & dmask) == pref) && (k & bmask)) ? 1 : 0;
            }
            if (tid == 0) s_cnt1 = 0;
            __syncthreads();
            if (mc) atomicAdd(&s_cnt1, (uint)mc);
            __syncthreads();
            if (tid == 0) {
                if ((int)s_cnt1 >= s_k) s_pref = pref | bmask;
                else s_k -= (int)s_cnt1;
            }
            __syncthreads();
        }
        if (tid == 0) s_thf = key2f(s_pref);
    }
    __syncthreads();
    const float thf = s_thf;

    // 6. final compaction of kept entries (>= thf), zero-padded to 64
    int kc = 0;
#pragma unroll
    for (int i = 0; i < VPT; ++i) kc += (vals[i] >= thf) ? 1 : 0;
    int p2 = kc;
#pragma unroll
    for (int off = 1; off < 64; off <<= 1) {
        int n = __shfl_up(p2, off, 64);
        if (lane >= off) p2 += n;
    }
    if (lane == 63) s_wsum[wid] = (uint)p2;
    __syncthreads();
    int kbase = p2 - kc;
    for (int w = 0; w < wid; ++w) kbase += (int)s_wsum[w];
    {
        int slot = kbase;
#pragma unroll
        for (int i = 0; i < VPT; ++i) {
            if (vals[i] >= thf) {
                if (slot < 64) {
                    list_m[slot] = (uint)(tid + (i << 8));
                    list_v[slot] = vals[i];
                }
                slot++;
            }
        }
    }
    __syncthreads();

    // 7. out[b][c] = b2[c] + sum_j v_j * w2t[m_j][c]  (fully unrolled, padded)
    if (tid < NB_CLASSES) {
        float a0 = b2[tid], a1 = 0.0f;
#pragma unroll
        for (int j = 0; j < 64; j += 2) {
            const uint m0 = list_m[j], m1 = list_m[j + 1];
            float w0, w1;
            if (USE_W2T) {
                w0 = w2t[(size_t)m0 * NB_CLASSES + tid];
                w1 = w2t[(size_t)m1 * NB_CLASSES + tid];
            } else {
                w0 = fmaxf(w2[(size_t)tid * MB_DIM + m0], 0.0f);
                w1 = fmaxf(w2[(size_t)tid * MB_DIM + m1], 0.0f);
            }
            a0 = fmaf(list_v[j],     w0, a0);
            a1 = fmaf(list_v[j + 1], w1, a1);
        }
        out[(size_t)brow * NB_CLASSES + tid] = a0 + a1;
    }
}

// ---------------------------------------------------------------------------
extern "C" void kernel_launch(void* const* d_in, const int* in_sizes, int n_in,
                              void* d_out, int out_size, void* d_ws, size_t ws_size,
                              hipStream_t stream) {
    const float* x  = (const float*)d_in[0];
    const float* w1 = (const float*)d_in[1];
    const float* w2 = (const float*)d_in[2];
    const float* b2 = (const float*)d_in[3];
    float* out = (float*)d_out;

    uint2* idx2 = (uint2*)d_ws;                            // 81920 B
    uint*  ovfc = (uint*)((char*)d_ws + 81920);            // 4 B
    uint2* ovfe = (uint2*)((char*)d_ws + 81928);           // 4096 B
    const size_t W2T_OFF = 131072;
    float* w2t = (float*)((char*)d_ws + W2T_OFF);
    const bool use_w2t =
        ws_size >= W2T_OFF + (size_t)MB_DIM * NB_CLASSES * sizeof(float);

    hipMemsetAsync(ovfc, 0, sizeof(uint), stream);
    k_extract<<<(MB_DIM * 64) / 256, 256, 0, stream>>>(w1, idx2, ovfc, ovfe);
    if (use_w2t) {
        k_w2t<<<(MB_DIM * NB_CLASSES + 255) / 256, 256, 0, stream>>>(w2, w2t);
        k_main<true><<<BATCH, NTHR, 0, stream>>>(x, idx2, ovfc, ovfe, w2t, w2, b2, out);
    } else {
        k_main<false><<<BATCH, NTHR, 0, stream>>>(x, idx2, ovfc, ovfe, nullptr, w2, b2, out);
    }
}